// Round 8
// baseline (44.601 us; speedup 1.0000x reference)
//
#include <hip/hip_runtime.h>
#include <math.h>

#define BLK 100          // BLOCK
#define NF  128          // N_freqs
#define NTOT (NF * BLK)  // 12800
#define NT  512          // 8 waves = 16 half-wave streams, 2 waves/SIMD
#define NR  7            // reg row slots per stream (16 x 7 = 112 >= 100)

__device__ __forceinline__ float4 fnma4(float4 v, float s, const float4 p) {
    v.x -= s * p.x; v.y -= s * p.y; v.z -= s * p.z; v.w -= s * p.w; return v;
}

// Broadcast x from lane `lo` (lower half-wave) / `lo+32` (upper half-wave).
__device__ __forceinline__ float rdl2(float x, int lo, int hsel) {
    const float a = __uint_as_float(__builtin_amdgcn_readlane(__float_as_uint(x), lo));
    const float b = __uint_as_float(__builtin_amdgcn_readlane(__float_as_uint(x), lo + 32));
    return hsel ? b : a;
}

// One workgroup (512 thr) per frequency block. The 100x100 matrix lives in
// REGISTERS: stream sid (half-wave) owns rows r = sid + 16j (j<7), lane g
// holds float4 column group g of each owned row. Per rank-4 phase:
//   - read 4-row panel from a tiny double-buffered LDS buffer (4 uniform +
//     4 per-lane b128 reads -- the ONLY LDS reads in the kernel),
//   - redundantly factor the 4x4 panel in registers (no cross-lane ops),
//   - sweep owned rows r > k0+3 in pure registers; `pan` (the row's
//     panel-column group) is broadcast from lane gp via v_readlane,
//   - owners of rows k0+4..k0+7 publish them to the other panel buffer.
// 1 barrier per phase. logdet accumulates as mantissa*2^e product (frexpf);
// one logf at the end. No column masking: updating dead (L-region) groups
// is the correct L-multiplier math and is never read as U.
__global__ __launch_bounds__(NT) void lu_logdet_kernel(const float* __restrict__ w,
                                                       const float* __restrict__ L,
                                                       float* __restrict__ out) {
    __shared__ float4 pbuf[2][4][26];   // [buf][panel row][column group]

    const int f    = blockIdx.x;
    const int tid  = threadIdx.x;
    const int sid  = tid >> 5;          // stream (half-wave) 0..15
    const int g    = tid & 31;          // float4 column group, valid if g < 25
    const int gg   = (g < 25) ? g : 24; // clamped for in-bounds panel reads
    const int hsel = (tid & 32) ? 1 : 0;

    float4 regs[NR];

    // ---- load owned rows straight to registers, fused transform:
    //      M[r][c] = s_r * D[r][c] + (r==c ? 1-s_r : 0)
    const float* base = L + (size_t)f * BLK * NTOT + (size_t)f * BLK;
    #pragma unroll
    for (int j = 0; j < NR; ++j) {
        const int r = sid + 16 * j;
        float4 m = make_float4(0.f, 0.f, 0.f, 0.f);
        if (r < BLK && g < 25) {
            const int c0 = 4 * g;
            const float4 v = *reinterpret_cast<const float4*>(base + (size_t)r * NTOT + c0);
            const float sv = 1.0f / (1.0f + expf(-w[f * BLK + r]));
            const float ds = 1.0f - sv;
            m.x = sv * v.x + ((c0 + 0) == r ? ds : 0.0f);
            m.y = sv * v.y + ((c0 + 1) == r ? ds : 0.0f);
            m.z = sv * v.z + ((c0 + 2) == r ? ds : 0.0f);
            m.w = sv * v.w + ((c0 + 3) == r ? ds : 0.0f);
        }
        regs[j] = m;
    }

    // ---- prologue: streams 0..3 publish rows 0..3 (their j=0 slot)
    if (sid < 4 && g < 25) pbuf[0][sid][g] = regs[0];
    __syncthreads();

    float mant = 1.0f;   // running product mantissa (frexp-normalized)
    int   e2   = 0;      // running exponent
    int   lneg = 0;      // count of negative diagonal entries

    for (int k0 = 0; k0 < BLK; k0 += 4) {
        const int gp = k0 >> 2;
        const int b  = gp & 1;
        const int nb = b ^ 1;

        // ---- panel in: 4 uniform (broadcast) + 4 per-lane b128 reads
        float4 pp0 = pbuf[b][0][gp];
        float4 pp1 = pbuf[b][1][gp];
        float4 pp2 = pbuf[b][2][gp];
        float4 pp3 = pbuf[b][3][gp];
        float4 P0  = pbuf[b][0][gg];
        float4 P1  = pbuf[b][1][gg];
        float4 P2  = pbuf[b][2][gg];
        float4 P3  = pbuf[b][3][gg];

        // ---- redundant in-register 4x4 panel factorization
        const float d0 = pp0.x, r0i = 1.0f / d0;
        float fc;
        fc = pp1.x * r0i;  pp1 = fnma4(pp1, fc, pp0);  P1 = fnma4(P1, fc, P0);
        const float d1 = pp1.y, r1i = 1.0f / d1;
        fc = pp2.x * r0i;  pp2 = fnma4(pp2, fc, pp0);  P2 = fnma4(P2, fc, P0);
        fc = pp2.y * r1i;  pp2 = fnma4(pp2, fc, pp1);  P2 = fnma4(P2, fc, P1);
        const float d2 = pp2.z, r2i = 1.0f / d2;
        fc = pp3.x * r0i;  pp3 = fnma4(pp3, fc, pp0);  P3 = fnma4(P3, fc, P0);
        fc = pp3.y * r1i;  pp3 = fnma4(pp3, fc, pp1);  P3 = fnma4(P3, fc, P1);
        fc = pp3.z * r2i;  pp3 = fnma4(pp3, fc, pp2);  P3 = fnma4(P3, fc, P2);
        const float d3 = pp3.w, r3i = 1.0f / d3;

        // ---- accumulate log-magnitude as normalized product + exponent
        mant *= d0 * d1 * d2 * d3;
        { int t; mant = frexpf(mant, &t); e2 += t; }
        lneg += (d0 < 0.0f) + (d1 < 0.0f) + (d2 < 0.0f) + (d3 < 0.0f);

        // ---- sweep owned rows (pure registers) + publish next panel rows
        const int khi = k0 + 3;
        #pragma unroll
        for (int j = 0; j < NR; ++j) {
            const int r = sid + 16 * j;
            if (r > khi && r < BLK) {
                float4 pan;
                pan.x = rdl2(regs[j].x, gp, hsel);
                pan.y = rdl2(regs[j].y, gp, hsel);
                pan.z = rdl2(regs[j].z, gp, hsel);
                pan.w = rdl2(regs[j].w, gp, hsel);
                const float f0 = pan.x * r0i;
                const float f1 = (pan.y - f0 * pp0.y) * r1i;
                const float f2 = (pan.z - f0 * pp0.z - f1 * pp1.z) * r2i;
                const float f3 = (pan.w - f0 * pp0.w - f1 * pp1.w - f2 * pp2.w) * r3i;
                float4 v = regs[j];
                v = fnma4(v, f0, P0); v = fnma4(v, f1, P1);
                v = fnma4(v, f2, P2); v = fnma4(v, f3, P3);
                regs[j] = v;
                if (r <= khi + 4 && g < 25) pbuf[nb][r - (k0 + 4)][g] = v;
            }
        }
        __syncthreads();
    }

    // ---- every thread holds the full result redundantly; thread 0 publishes
    if (tid == 0) {
        float ld = logf(mant) + (float)e2 * 0.69314718055994531f;
        if ((lneg & 1) || !isfinite(ld)) ld = __int_as_float(0x7fc00000);  // NaN
        out[1 + f] = ld;
        atomicAdd(out, ld);   // out[0] zeroed via memset before launch; NaN propagates
    }
}

extern "C" void kernel_launch(void* const* d_in, const int* in_sizes, int n_in,
                              void* d_out, int out_size, void* d_ws, size_t ws_size,
                              hipStream_t stream) {
    const float* w = (const float*)d_in[0];   // weights (12800,) f32
    const float* L = (const float*)d_in[1];   // L_kernel (12800,12800) f32
    float* out = (float*)d_out;               // [0]=sum, [1..128]=logdets
    hipMemsetAsync(d_out, 0, sizeof(float), stream);   // zero the atomic accumulator
    lu_logdet_kernel<<<NF, NT, 0, stream>>>(w, L, out);
}

// Round 9
// 41.667 us; speedup vs baseline: 1.0704x; 1.0704x over previous
//
#include <hip/hip_runtime.h>
#include <math.h>

#define BLK 100          // BLOCK
#define NF  128          // N_freqs
#define NTOT (NF * BLK)  // 12800
#define NT  512          // 8 waves = 16 half-wave streams, 2 waves/SIMD
#define NR  7            // reg row slots per stream (16 x 7 = 112 >= 100)

__device__ __forceinline__ float4 fnma4(float4 v, float s, const float4 p) {
    v.x -= s * p.x; v.y -= s * p.y; v.z -= s * p.z; v.w -= s * p.w; return v;
}

// One workgroup (512 thr) per frequency block. Matrix in REGISTERS:
// stream sid (half-wave) owns rows r = sid + 16j (j<7); lane g holds float4
// column group g. Cross-lane data flows through two tiny double-buffered LDS
// structures, all reads uniform-per-half-wave (broadcast, ~free):
//   panc[b][r] : row r's current panel column group (float4)  -> `pan`, `pp`
//   pbuf[b][m][g] : full pivot rows k0..k0+3                  -> `P` (per-lane)
// Per phase: read pp (4 uniform) + P (4 per-lane), redundantly factor the 4x4
// panel in registers, sweep owned rows in pure registers (pan = 1 uniform
// read/slot), lane g==gp+1 writes the updated row's next panel group to
// panc[nb], owners of rows k0+4..k0+7 publish full rows to pbuf[nb].
// Dead slots skipped by wave-uniform j<js branch. 1 barrier/phase.
__global__ __launch_bounds__(NT) void lu_logdet_kernel(const float* __restrict__ w,
                                                       const float* __restrict__ L,
                                                       float* __restrict__ out) {
    __shared__ float4 panc[2][BLK];     // [buf][row] panel column group
    __shared__ float4 pbuf[2][4][32];   // [buf][pivot row][column group], padded

    const int f   = blockIdx.x;
    const int tid = threadIdx.x;
    const int sid = tid >> 5;           // stream (half-wave) 0..15
    const int g   = tid & 31;           // float4 column group, valid if g < 25

    float4 regs[NR];

    // ---- load owned rows straight to registers, fused transform:
    //      M[r][c] = s_r * D[r][c] + (r==c ? 1-s_r : 0)
    const float* base = L + (size_t)f * BLK * NTOT + (size_t)f * BLK;
    #pragma unroll
    for (int j = 0; j < NR; ++j) {
        const int r = sid + 16 * j;
        float4 m = make_float4(0.f, 0.f, 0.f, 0.f);
        if (r < BLK && g < 25) {
            const int c0 = 4 * g;
            const float4 v = *reinterpret_cast<const float4*>(base + (size_t)r * NTOT + c0);
            const float sv = 1.0f / (1.0f + expf(-w[f * BLK + r]));
            const float ds = 1.0f - sv;
            m.x = sv * v.x + ((c0 + 0) == r ? ds : 0.0f);
            m.y = sv * v.y + ((c0 + 1) == r ? ds : 0.0f);
            m.z = sv * v.z + ((c0 + 2) == r ? ds : 0.0f);
            m.w = sv * v.w + ((c0 + 3) == r ? ds : 0.0f);
        }
        regs[j] = m;
    }

    // ---- prologue: publish panel column 0 of all rows + pivot rows 0..3
    #pragma unroll
    for (int j = 0; j < NR; ++j) {
        const int r = sid + 16 * j;
        if (r < BLK && g == 0) panc[0][r] = regs[j];
    }
    if (sid < 4) pbuf[0][sid][g] = regs[0];   // rows 0..3 (pad makes g<32 safe)
    __syncthreads();

    float mant = 1.0f;   // running product mantissa (frexp-normalized)
    int   e2   = 0;      // running exponent
    int   lneg = 0;      // count of negative diagonal entries

    for (int k0 = 0; k0 < BLK; k0 += 4) {
        const int gp = k0 >> 2;
        const int b  = gp & 1;
        const int nb = b ^ 1;
        const int khi = k0 + 3;

        // ---- panel in: 4 fully-uniform reads (pp) + 4 per-lane reads (P)
        float4 pp0 = panc[b][k0 + 0];
        float4 pp1 = panc[b][k0 + 1];
        float4 pp2 = panc[b][k0 + 2];
        float4 pp3 = panc[b][k0 + 3];
        float4 P0  = pbuf[b][0][g];     // lanes g>=25 read pad garbage, discarded
        float4 P1  = pbuf[b][1][g];
        float4 P2  = pbuf[b][2][g];
        float4 P3  = pbuf[b][3][g];

        // ---- redundant in-register 4x4 panel factorization (no cross-lane ops)
        const float d0 = pp0.x, r0i = 1.0f / d0;
        float fc;
        fc = pp1.x * r0i;  pp1 = fnma4(pp1, fc, pp0);  P1 = fnma4(P1, fc, P0);
        const float d1 = pp1.y, r1i = 1.0f / d1;
        fc = pp2.x * r0i;  pp2 = fnma4(pp2, fc, pp0);  P2 = fnma4(P2, fc, P0);
        fc = pp2.y * r1i;  pp2 = fnma4(pp2, fc, pp1);  P2 = fnma4(P2, fc, P1);
        const float d2 = pp2.z, r2i = 1.0f / d2;
        fc = pp3.x * r0i;  pp3 = fnma4(pp3, fc, pp0);  P3 = fnma4(P3, fc, P0);
        fc = pp3.y * r1i;  pp3 = fnma4(pp3, fc, pp1);  P3 = fnma4(P3, fc, P1);
        fc = pp3.z * r2i;  pp3 = fnma4(pp3, fc, pp2);  P3 = fnma4(P3, fc, P2);
        const float d3 = pp3.w, r3i = 1.0f / d3;

        // ---- accumulate log-magnitude as normalized product + exponent
        mant *= d0 * d1 * d2 * d3;
        { int t; mant = frexpf(mant, &t); e2 += t; }
        lneg += (d0 < 0.0f) + (d1 < 0.0f) + (d2 < 0.0f) + (d3 < 0.0f);

        // ---- sweep owned rows in registers; pan via uniform LDS read
        const int js = (k0 + 4) >> 4;   // first slot with any active stream
        #pragma unroll
        for (int j = 0; j < NR; ++j) {
            if (j < js) continue;       // wave-uniform scalar skip
            const int r = sid + 16 * j;
            if (r > khi && r < BLK) {
                const float4 pan = panc[b][r];   // half-wave broadcast read
                const float f0 = pan.x * r0i;
                const float f1 = (pan.y - f0 * pp0.y) * r1i;
                const float f2 = (pan.z - f0 * pp0.z - f1 * pp1.z) * r2i;
                const float f3 = (pan.w - f0 * pp0.w - f1 * pp1.w - f2 * pp2.w) * r3i;
                float4 v = regs[j];
                v = fnma4(v, f0, P0); v = fnma4(v, f1, P1);
                v = fnma4(v, f2, P2); v = fnma4(v, f3, P3);
                regs[j] = v;
                if (g == gp + 1) panc[nb][r] = v;                    // next pan col
                if ((unsigned)(r - (k0 + 4)) < 4u)                   // next pivot rows
                    pbuf[nb][r - (k0 + 4)][g] = v;
            }
        }
        __syncthreads();
    }

    // ---- every thread holds the full result redundantly; thread 0 publishes
    if (tid == 0) {
        float ld = logf(mant) + (float)e2 * 0.69314718055994531f;
        if ((lneg & 1) || !isfinite(ld)) ld = __int_as_float(0x7fc00000);  // NaN
        out[1 + f] = ld;
        atomicAdd(out, ld);   // out[0] zeroed via memset before launch; NaN propagates
    }
}

extern "C" void kernel_launch(void* const* d_in, const int* in_sizes, int n_in,
                              void* d_out, int out_size, void* d_ws, size_t ws_size,
                              hipStream_t stream) {
    const float* w = (const float*)d_in[0];   // weights (12800,) f32
    const float* L = (const float*)d_in[1];   // L_kernel (12800,12800) f32
    float* out = (float*)d_out;               // [0]=sum, [1..128]=logdets
    hipMemsetAsync(d_out, 0, sizeof(float), stream);   // zero the atomic accumulator
    lu_logdet_kernel<<<NF, NT, 0, stream>>>(w, L, out);
}

// Round 10
// 39.622 us; speedup vs baseline: 1.1257x; 1.0516x over previous
//
#include <hip/hip_runtime.h>
#include <math.h>

#define BLK 100          // BLOCK
#define NF  128          // N_freqs
#define NTOT (NF * BLK)  // 12800
#define P   104          // LDS pitch (floats): rows 16B-aligned (416B)
#define NT  1024         // 16 waves = 4 waves/SIMD -> TLP hides chains/latency
#define NS  32           // half-wave sweep streams

__device__ __forceinline__ float4 fnma4(float4 v, float s, const float4 p) {
    v.x -= s * p.x; v.y -= s * p.y; v.z -= s * p.z; v.w -= s * p.w; return v;
}

#define LD4(r, c4) (*reinterpret_cast<float4*>(&a[(r) * P + 4 * (c4)]))

// One workgroup (1024 thr, 16 waves) per frequency block. Rank-4 blocked
// non-pivoted LU in LDS, ONE barrier per phase. Every lane redundantly
// factors the 4x4 panel in registers from the broadcast panel column group
// (no cross-lane ops, no pivot-row writeback). 4 waves/SIMD interleave the
// panel chains, LDS latencies and barrier drains. diag -> LDS (thread 0);
// logf once, in parallel, in the epilogue.
__global__ __launch_bounds__(NT) void lu_logdet_kernel(const float* __restrict__ w,
                                                       const float* __restrict__ L,
                                                       float* __restrict__ out) {
    __shared__ float a[BLK * P];
    __shared__ float diag[BLK];
    __shared__ float ps[2];
    __shared__ int   pn[2];

    const int f   = blockIdx.x;
    const int tid = threadIdx.x;
    const int sid = tid >> 5;        // 32 half-wave streams
    const int g   = tid & 31;        // float4 column group
    const int gg  = (g < 25) ? g : 24;   // clamped, keeps inactive lanes in-bounds

    // ---- load diag block f, fused transform: M[r][c] = s_r*D[r][c] + (r==c ? 1-s_r : 0)
    const float* base = L + (size_t)f * BLK * NTOT + (size_t)f * BLK;
    for (int q = tid; q < BLK * 25; q += NT) {         // 25 float4 per row
        const int r  = q / 25;
        const int c0 = (q - r * 25) * 4;
        const float4 v = *reinterpret_cast<const float4*>(base + (size_t)r * NTOT + c0);
        const float sv = 1.0f / (1.0f + expf(-w[f * BLK + r]));
        const float ds = 1.0f - sv;
        float4 m;
        m.x = sv * v.x + ((c0 + 0) == r ? ds : 0.0f);
        m.y = sv * v.y + ((c0 + 1) == r ? ds : 0.0f);
        m.z = sv * v.z + ((c0 + 2) == r ? ds : 0.0f);
        m.w = sv * v.w + ((c0 + 3) == r ? ds : 0.0f);
        *reinterpret_cast<float4*>(&a[r * P + c0]) = m;
    }
    __syncthreads();

    for (int k0 = 0; k0 < BLK; k0 += 4) {
        const int gp = k0 >> 2;

        // ---- redundant in-register panel factorization (no cross-lane ops)
        float4 pp0 = LD4(k0 + 0, gp);    // broadcast reads (uniform addr)
        float4 pp1 = LD4(k0 + 1, gp);
        float4 pp2 = LD4(k0 + 2, gp);
        float4 pp3 = LD4(k0 + 3, gp);
        float4 P0  = LD4(k0 + 0, gg);    // this lane's column group of pivot rows
        float4 P1  = LD4(k0 + 1, gg);
        float4 P2  = LD4(k0 + 2, gg);
        float4 P3  = LD4(k0 + 3, gg);

        const float d0 = pp0.x, r0i = 1.0f / d0;
        float fc;
        fc = pp1.x * r0i;  pp1 = fnma4(pp1, fc, pp0);  P1 = fnma4(P1, fc, P0);
        const float d1 = pp1.y, r1i = 1.0f / d1;
        fc = pp2.x * r0i;  pp2 = fnma4(pp2, fc, pp0);  P2 = fnma4(P2, fc, P0);
        fc = pp2.y * r1i;  pp2 = fnma4(pp2, fc, pp1);  P2 = fnma4(P2, fc, P1);
        const float d2 = pp2.z, r2i = 1.0f / d2;
        fc = pp3.x * r0i;  pp3 = fnma4(pp3, fc, pp0);  P3 = fnma4(P3, fc, P0);
        fc = pp3.y * r1i;  pp3 = fnma4(pp3, fc, pp1);  P3 = fnma4(P3, fc, P1);
        fc = pp3.z * r2i;  pp3 = fnma4(pp3, fc, pp2);  P3 = fnma4(P3, fc, P2);
        const float d3 = pp3.w, r3i = 1.0f / d3;

        if (tid == 0) {
            diag[k0 + 0] = d0; diag[k0 + 1] = d1;
            diag[k0 + 2] = d2; diag[k0 + 3] = d3;
        }

        // ---- sweep: rank-4 update of rows k0+4..99, 32 streams, groups > gp
#define FACS(pan, f0, f1, f2, f3)                                             \
        const float f0 = pan.x * r0i;                                         \
        const float f1 = (pan.y - f0 * pp0.y) * r1i;                          \
        const float f2 = (pan.z - f0 * pp0.z - f1 * pp1.z) * r2i;             \
        const float f3 = (pan.w - f0 * pp0.w - f1 * pp1.w - f2 * pp2.w) * r3i;

        if (g > gp && g < 25) {
            int i = k0 + 4 + sid;
            if (i + NS < BLK) {
                const int i2 = i + NS;
                const float4 panA = LD4(i,  gp);
                const float4 panB = LD4(i2, gp);
                float4 vA = LD4(i,  g);
                float4 vB = LD4(i2, g);
                FACS(panA, a0, a1, a2, a3)
                FACS(panB, b0, b1, b2, b3)
                vA = fnma4(vA, a0, P0); vA = fnma4(vA, a1, P1);
                vA = fnma4(vA, a2, P2); vA = fnma4(vA, a3, P3);
                vB = fnma4(vB, b0, P0); vB = fnma4(vB, b1, P1);
                vB = fnma4(vB, b2, P2); vB = fnma4(vB, b3, P3);
                LD4(i,  g) = vA;
                LD4(i2, g) = vB;
                i += 2 * NS;
            }
            for (; i < BLK; i += NS) {
                const float4 pan = LD4(i, gp);
                float4 v = LD4(i, g);
                FACS(pan, c0, c1, c2, c3)
                v = fnma4(v, c0, P0); v = fnma4(v, c1, P1);
                v = fnma4(v, c2, P2); v = fnma4(v, c3, P3);
                LD4(i, g) = v;
            }
        }
#undef FACS
        __syncthreads();
    }

    // ---- epilogue: parallel logf over diag, shuffle reduce (waves 0-1 only)
    float lsum = 0.0f;
    int   lneg = 0;
    if (tid < BLK) {
        const float d = diag[tid];
        lsum = logf(fabsf(d));                   // d==0 -> -inf -> caught below
        lneg = (d < 0.0f) ? 1 : 0;
    }
    if (tid < 128) {
        for (int off = 32; off > 0; off >>= 1) {
            lsum += __shfl_down(lsum, off);
            lneg += __shfl_down(lneg, off);
        }
        if ((tid & 63) == 0) { ps[tid >> 6] = lsum; pn[tid >> 6] = lneg; }
    }
    __syncthreads();
    if (tid == 0) {
        float ld = ps[0] + ps[1];
        const int n = pn[0] + pn[1];
        if ((n & 1) || !isfinite(ld)) ld = __int_as_float(0x7fc00000);  // NaN
        out[1 + f] = ld;
        atomicAdd(out, ld);   // out[0] zeroed via memset before launch; NaN propagates
    }
}

extern "C" void kernel_launch(void* const* d_in, const int* in_sizes, int n_in,
                              void* d_out, int out_size, void* d_ws, size_t ws_size,
                              hipStream_t stream) {
    const float* w = (const float*)d_in[0];   // weights (12800,) f32
    const float* L = (const float*)d_in[1];   // L_kernel (12800,12800) f32
    float* out = (float*)d_out;               // [0]=sum, [1..128]=logdets
    hipMemsetAsync(d_out, 0, sizeof(float), stream);   // zero the atomic accumulator
    lu_logdet_kernel<<<NF, NT, 0, stream>>>(w, L, out);
}